// Round 1
// baseline (749.650 us; speedup 1.0000x reference)
//
#include <hip/hip_runtime.h>

// GRUObservationCellLogvar: N=500000, N_OBS=200000, D=32, H=128, P=4
// out = [ h_updated (500000*128) | losses (200000*32) ] fp32
//
// Round 1: correct fp32 implementation.
//   k_transpose: W_ih/W_hh [384x128] -> WT [2][128][384] in ws (coalesced inner-loop reads)
//   k_copy:      h -> out_h (float4 grid-stride)
//   k_main:      per 16 observed rows: prep (losses + gru_in into LDS), gather h rows,
//                dual-GEMM (fp32 FMA, 1 col x 8 rows per thread), GRU epilogue, scatter.

constexpr int HDIM = 128;   // H
constexpr int GDIM = 384;   // 3H
constexpr int WELEMS = GDIM * HDIM;  // 49152 per weight matrix

__global__ __launch_bounds__(256) void k_transpose(const float* __restrict__ W_ih,
                                                   const float* __restrict__ W_hh,
                                                   float* __restrict__ WT) {
    int i = blockIdx.x * 256 + threadIdx.x;      // 0 .. 2*49152-1
    bool second = (i >= WELEMS);
    const float* src = second ? W_hh : W_ih;
    float* dst = WT + (second ? WELEMS : 0);
    int ii = second ? (i - WELEMS) : i;
    int j = ii >> 7;      // gate-row in [0,384)
    int k = ii & 127;     // k in [0,128)
    dst[k * GDIM + j] = src[ii];
}

__global__ __launch_bounds__(256) void k_copy(const float4* __restrict__ src,
                                              float4* __restrict__ dst, long n4) {
    long i = (long)blockIdx.x * blockDim.x + threadIdx.x;
    long stride = (long)gridDim.x * blockDim.x;
    for (; i < n4; i += stride) dst[i] = src[i];
}

__global__ __launch_bounds__(256) void k_main(
    const float* __restrict__ h,
    const float* __restrict__ p,
    const float* __restrict__ X_obs,
    const float* __restrict__ M_obs,
    const int*   __restrict__ i_obs,
    const float* __restrict__ w_prep,     // [32][4][4]
    const float* __restrict__ bias_prep,  // [32][4]
    const float* __restrict__ WT,         // [2][128][384]
    const float* __restrict__ b_ih,       // [384]
    const float* __restrict__ b_hh,       // [384]
    float* __restrict__ out_h,
    float* __restrict__ out_losses)
{
    __shared__ float sAg[16][128];   // gru_in tile
    __shared__ float sAh[16][128];   // h_obs tile
    __shared__ int   sIdx[16];

    const int tid  = threadIdx.x;
    const int row0 = blockIdx.x * 16;

    if (tid < 16) sIdx[tid] = i_obs[row0 + tid];
    __syncthreads();

    // ---- prep phase: 8 rows x 32 channels per pass, 2 passes ----
    {
        const int d  = tid & 31;
        const int r8 = tid >> 5;
        float wp[16];
        #pragma unroll
        for (int t = 0; t < 16; ++t) wp[t] = w_prep[d * 16 + t];
        float bp[4];
        #pragma unroll
        for (int t = 0; t < 4; ++t) bp[t] = bias_prep[d * 4 + t];

        #pragma unroll
        for (int rp = 0; rp < 2; ++rp) {
            const int r   = rp * 8 + r8;
            const int row = row0 + r;
            const int idx = sIdx[r];
            const float mean   = p[(size_t)idx * 64 + d];
            const float logvar = p[(size_t)idx * 64 + 32 + d];
            const float X = X_obs[(size_t)row * 32 + d];
            const float M = M_obs[(size_t)row * 32 + d];
            const float lv  = fminf(fmaxf(logvar, -10.f), 10.f);
            const float sig = fminf(fmaxf(expf(0.5f * lv), 1e-6f), 1e6f);
            const float err = fminf(fmaxf((X - mean) / sig, -1e6f), 1e6f);
            // 2*log(sqrt(2*pi)) = log(2*pi)
            out_losses[(size_t)row * 32 + d] = 0.5f * ((err * err + lv + 1.8378770664093453f) * M);
            #pragma unroll
            for (int q = 0; q < 4; ++q) {
                float g = X * wp[q] + mean * wp[4 + q] + lv * wp[8 + q] + err * wp[12 + q] + bp[q];
                sAg[r][d * 4 + q] = fmaxf(g, 0.f) * M;
            }
        }
        // gather 16 h rows (32 float4 per row), 2 passes of 256 float4
        #pragma unroll
        for (int pass = 0; pass < 2; ++pass) {
            int li = pass * 256 + tid;
            int r  = li >> 5;
            int c4 = li & 31;
            float4 v = ((const float4*)(h + (size_t)sIdx[r] * 128))[c4];
            *(float4*)&sAh[r][c4 * 4] = v;
        }
    }
    __syncthreads();

    // ---- GEMM phase: thread = (col c, row-group rg of 8 rows) ----
    const int c     = tid & 127;
    const int rbase = (tid >> 7) * 8;

    float accR[8] = {}, accZ[8] = {}, accIN[8] = {}, accHN[8] = {};

    const float* Wi = WT + c;            // WT_ih[k][gate*128+c], stride 384 per k
    const float* Wh = WT + WELEMS + c;

    #pragma unroll 4
    for (int k = 0; k < 128; ++k) {
        const float wir = Wi[k * GDIM];
        const float wiz = Wi[k * GDIM + 128];
        const float win = Wi[k * GDIM + 256];
        const float whr = Wh[k * GDIM];
        const float whz = Wh[k * GDIM + 128];
        const float whn = Wh[k * GDIM + 256];
        #pragma unroll
        for (int r = 0; r < 8; ++r) {
            const float ag = sAg[rbase + r][k];   // wave-broadcast LDS read
            const float ah = sAh[rbase + r][k];
            accR[r]  = fmaf(ag, wir, accR[r]);
            accR[r]  = fmaf(ah, whr, accR[r]);
            accZ[r]  = fmaf(ag, wiz, accZ[r]);
            accZ[r]  = fmaf(ah, whz, accZ[r]);
            accIN[r] = fmaf(ag, win, accIN[r]);
            accHN[r] = fmaf(ah, whn, accHN[r]);
        }
    }

    const float bir = b_ih[c]       + b_hh[c];
    const float biz = b_ih[128 + c] + b_hh[128 + c];
    const float bin = b_ih[256 + c];
    const float bhn = b_hh[256 + c];

    #pragma unroll
    for (int r = 0; r < 8; ++r) {
        const int rr = rbase + r;
        const float x_r = accR[r] + bir;
        const float x_z = accZ[r] + biz;
        const float i_n = accIN[r] + bin;
        const float h_n = accHN[r] + bhn;
        const float rg = 1.f / (1.f + expf(-x_r));
        const float zg = 1.f / (1.f + expf(-x_z));
        const float ng = tanhf(fmaf(rg, h_n, i_n));
        const float hp = sAh[rr][c];
        // (1-z)*n + z*h = n + z*(h-n)
        out_h[(size_t)sIdx[rr] * 128 + c] = fmaf(zg, hp - ng, ng);
    }
}

extern "C" void kernel_launch(void* const* d_in, const int* in_sizes, int n_in,
                              void* d_out, int out_size, void* d_ws, size_t ws_size,
                              hipStream_t stream) {
    const float* h         = (const float*)d_in[0];
    const float* p         = (const float*)d_in[1];
    const float* X_obs     = (const float*)d_in[2];
    const float* M_obs     = (const float*)d_in[3];
    const int*   i_obs     = (const int*)d_in[4];
    const float* w_prep    = (const float*)d_in[5];
    const float* bias_prep = (const float*)d_in[6];
    const float* W_ih      = (const float*)d_in[7];
    const float* W_hh      = (const float*)d_in[8];
    const float* b_ih      = (const float*)d_in[9];
    const float* b_hh      = (const float*)d_in[10];

    const int Nh   = in_sizes[0] / 128;   // 500000
    const int NOBS = in_sizes[4];         // 200000

    float* out_h      = (float*)d_out;
    float* out_losses = out_h + (size_t)Nh * 128;
    float* WT         = (float*)d_ws;     // 2*49152 floats = 393216 B

    // 1) transpose weights into ws
    hipLaunchKernelGGL(k_transpose, dim3((2 * WELEMS) / 256), dim3(256), 0, stream,
                       W_ih, W_hh, WT);
    // 2) copy h -> out_h
    long n4 = (long)Nh * 128 / 4;
    hipLaunchKernelGGL(k_copy, dim3(2048), dim3(256), 0, stream,
                       (const float4*)h, (float4*)out_h, n4);
    // 3) fused prep + dual-GEMM + GRU + scatter (16 rows per block)
    hipLaunchKernelGGL(k_main, dim3(NOBS / 16), dim3(256), 0, stream,
                       h, p, X_obs, M_obs, i_obs, w_prep, bias_prep, WT,
                       b_ih, b_hh, out_h, out_losses);
}

// Round 2
// 270.554 us; speedup vs baseline: 2.7708x; 2.7708x over previous
//
#include <hip/hip_runtime.h>

// GRUObservationCellLogvar — R2: bf16-MFMA dual-GEMM.
// N=500000, N_OBS=200000, D=32, H=128, P=4
// out = [ h_updated (500000*128) | losses (200000*32) ] fp32
//
// k_prepack: W_ih/W_hh f32 -> bf16 MFMA B-fragments in ws (192 KB).
//            Padded-gate layout per wave w (16 cols): frags f=0..23:
//            f 0-7  : R gate,  k-steps 0..7 (k=0..255 over [gru_in|h])
//            f 8-15 : Z gate,  k-steps 0..7
//            f 16-19: IN gate, k-steps 0..3 (k<128, gru_in only)
//            f 20-23: HN gate, k-steps 4..7 (k>=128, h only)
// k_copy:    h -> out_h (float4 grid-stride)  [updated rows overwritten later]
// k_main:    64 rows/block, 512 thr. Prep writes losses + A (bf16 frag layout,
//            32KB LDS); 8 waves x mfma_f32_16x16x32_bf16; fp32 GRU epilogue.

typedef __attribute__((ext_vector_type(8))) short bf16x8;
typedef __attribute__((ext_vector_type(4))) float f32x4;

__device__ inline unsigned short f2bf(float x) {
    union { float f; unsigned int u; } v; v.f = x;
    unsigned int r = (v.u + 0x7fffu + ((v.u >> 16) & 1u)) >> 16;  // RNE
    return (unsigned short)r;
}

// ---- B prepack: 98304 bf16 elems = 8 waves * 24 frags * 64 lanes * 8 ----
__global__ __launch_bounds__(256) void k_prepack(const float* __restrict__ W_ih,
                                                 const float* __restrict__ W_hh,
                                                 unsigned short* __restrict__ B) {
    const int i = blockIdx.x * 256 + threadIdx.x;        // 0 .. 98303
    const int w    = i / 12288;                          // wave (col group)
    const int rem  = i - w * 12288;
    const int f    = rem >> 9;                           // frag 0..23
    const int rem2 = rem & 511;
    const int l    = rem2 >> 3;                          // lane 0..63
    const int j    = rem2 & 7;
    const int c    = w * 16 + (l & 15);                  // output col 0..127
    const int ko   = (l >> 4) * 8 + j;                   // k within 32-step
    float val;
    if (f < 8) {                                         // R gate, g = c
        const int k = f * 32 + ko;
        val = (k < 128) ? W_ih[c * 128 + k] : W_hh[c * 128 + (k - 128)];
    } else if (f < 16) {                                 // Z gate, g = 128+c
        const int k = (f - 8) * 32 + ko;
        val = (k < 128) ? W_ih[(128 + c) * 128 + k] : W_hh[(128 + c) * 128 + (k - 128)];
    } else if (f < 20) {                                 // IN gate, k<128
        const int k = (f - 16) * 32 + ko;
        val = W_ih[(256 + c) * 128 + k];
    } else {                                             // HN gate, k>=128
        const int k = (f - 20 + 4) * 32 + ko;
        val = W_hh[(256 + c) * 128 + (k - 128)];
    }
    B[i] = f2bf(val);
}

__global__ __launch_bounds__(256) void k_copy(const float4* __restrict__ src,
                                              float4* __restrict__ dst, long n4) {
    long i = (long)blockIdx.x * blockDim.x + threadIdx.x;
    long stride = (long)gridDim.x * blockDim.x;
    for (; i < n4; i += stride) dst[i] = src[i];
}

__global__ __launch_bounds__(512) void k_main(
    const float* __restrict__ h,
    const float* __restrict__ p,
    const float* __restrict__ X_obs,
    const float* __restrict__ M_obs,
    const int*   __restrict__ i_obs,
    const float* __restrict__ w_prep,     // [32][4][4]
    const float* __restrict__ bias_prep,  // [32][4]
    const unsigned short* __restrict__ Bpk,
    const float* __restrict__ b_ih,       // [384]
    const float* __restrict__ b_hh,       // [384]
    float* __restrict__ out_h,
    float* __restrict__ out_losses)
{
    // A fragments: [mt 0..3][ks 0..7][lane 0..63][8 bf16] = 32 KB
    __shared__ unsigned short sA[4 * 8 * 64 * 8];
    __shared__ int sIdx[64];

    const int tid  = threadIdx.x;
    const int row0 = blockIdx.x * 64;

    if (tid < 64) sIdx[tid] = i_obs[row0 + tid];
    __syncthreads();

    // ---- prep: losses + gru_in(bf16 frags) ; h gather -> bf16 frags ----
    {
        const int d = tid & 31;
        float wp[16], bp[4];
        #pragma unroll
        for (int t = 0; t < 16; ++t) wp[t] = w_prep[d * 16 + t];
        #pragma unroll
        for (int t = 0; t < 4; ++t) bp[t] = bias_prep[d * 4 + t];

        // frag coords for k = d*4..d*4+3 (gru_in part, k<128)
        const int ksA    = d >> 3;
        const int lane16A = (d >> 1) & 3;
        const int j0A    = (d & 1) * 4;

        #pragma unroll
        for (int pass = 0; pass < 4; ++pass) {
            const int r   = pass * 16 + (tid >> 5);
            const int row = row0 + r;
            const int idx = sIdx[r];
            const float mean   = p[(size_t)idx * 64 + d];
            const float logvar = p[(size_t)idx * 64 + 32 + d];
            const float X = X_obs[(size_t)row * 32 + d];
            const float M = M_obs[(size_t)row * 32 + d];
            const float lv  = fminf(fmaxf(logvar, -10.f), 10.f);
            const float sig = fminf(fmaxf(expf(0.5f * lv), 1e-6f), 1e6f);
            const float err = fminf(fmaxf((X - mean) / sig, -1e6f), 1e6f);
            out_losses[(size_t)row * 32 + d] =
                0.5f * ((err * err + lv + 1.8378770664093453f) * M);
            ushort4 u;
            {
                float g0 = fmaf(X, wp[0], fmaf(mean, wp[4], fmaf(lv, wp[8],  fmaf(err, wp[12], bp[0]))));
                float g1 = fmaf(X, wp[1], fmaf(mean, wp[5], fmaf(lv, wp[9],  fmaf(err, wp[13], bp[1]))));
                float g2 = fmaf(X, wp[2], fmaf(mean, wp[6], fmaf(lv, wp[10], fmaf(err, wp[14], bp[2]))));
                float g3 = fmaf(X, wp[3], fmaf(mean, wp[7], fmaf(lv, wp[11], fmaf(err, wp[15], bp[3]))));
                u.x = f2bf(fmaxf(g0, 0.f) * M);
                u.y = f2bf(fmaxf(g1, 0.f) * M);
                u.z = f2bf(fmaxf(g2, 0.f) * M);
                u.w = f2bf(fmaxf(g3, 0.f) * M);
            }
            const int mt   = r >> 4;
            const int lane = (r & 15) + lane16A * 16;
            *reinterpret_cast<ushort4*>(&sA[((mt * 8 + ksA) * 64 + lane) * 8 + j0A]) = u;
        }

        // h gather: k = 128 + c4*4
        const int c4     = tid & 31;
        const int ksH    = 4 + (c4 >> 3);
        const int lane16H = (c4 >> 1) & 3;
        const int j0H    = (c4 & 1) * 4;
        #pragma unroll
        for (int pass = 0; pass < 4; ++pass) {
            const int r = pass * 16 + (tid >> 5);
            const float4 v = *reinterpret_cast<const float4*>(h + (size_t)sIdx[r] * 128 + c4 * 4);
            ushort4 u;
            u.x = f2bf(v.x); u.y = f2bf(v.y); u.z = f2bf(v.z); u.w = f2bf(v.w);
            const int mt   = r >> 4;
            const int lane = (r & 15) + lane16H * 16;
            *reinterpret_cast<ushort4*>(&sA[((mt * 8 + ksH) * 64 + lane) * 8 + j0H]) = u;
        }
    }
    __syncthreads();

    // ---- MFMA phase: wave wid owns cols c = wid*16 + (lane&15), all 4 gates ----
    const int wid  = tid >> 6;
    const int lane = tid & 63;
    const int c    = wid * 16 + (lane & 15);

    bf16x8 breg[24];
    const bf16x8* bsrc = reinterpret_cast<const bf16x8*>(Bpk) + wid * 1536;
    #pragma unroll
    for (int f = 0; f < 24; ++f) breg[f] = bsrc[f * 64 + lane];

    const float bR  = b_ih[c]       + b_hh[c];
    const float bZ  = b_ih[128 + c] + b_hh[128 + c];
    const float bIN = b_ih[256 + c];
    const float bHN = b_hh[256 + c];

    const bf16x8* aptr = reinterpret_cast<const bf16x8*>(sA);

    #pragma unroll
    for (int mt = 0; mt < 4; ++mt) {
        f32x4 accR = {0.f, 0.f, 0.f, 0.f};
        f32x4 accZ = {0.f, 0.f, 0.f, 0.f};
        f32x4 accIN = {0.f, 0.f, 0.f, 0.f};
        f32x4 accHN = {0.f, 0.f, 0.f, 0.f};
        #pragma unroll
        for (int ks = 0; ks < 8; ++ks) {
            const bf16x8 af = aptr[(mt * 8 + ks) * 64 + lane];
            accR = __builtin_amdgcn_mfma_f32_16x16x32_bf16(af, breg[ks],     accR, 0, 0, 0);
            accZ = __builtin_amdgcn_mfma_f32_16x16x32_bf16(af, breg[8 + ks], accZ, 0, 0, 0);
            if (ks < 4) accIN = __builtin_amdgcn_mfma_f32_16x16x32_bf16(af, breg[16 + ks], accIN, 0, 0, 0);
            else        accHN = __builtin_amdgcn_mfma_f32_16x16x32_bf16(af, breg[16 + ks], accHN, 0, 0, 0);
        }
        // C/D layout: col = lane&15 (= our c), rows = (lane>>4)*4 + reg
        const int rbase = mt * 16 + (lane >> 4) * 4;
        #pragma unroll
        for (int reg = 0; reg < 4; ++reg) {
            const int idx  = sIdx[rbase + reg];
            const float hp = h[(size_t)idx * 128 + c];     // L2-hot re-read
            const float xr  = accR[reg]  + bR;
            const float xz  = accZ[reg]  + bZ;
            const float xin = accIN[reg] + bIN;
            const float xhn = accHN[reg] + bHN;
            const float rg = 1.f / (1.f + expf(-xr));
            const float zg = 1.f / (1.f + expf(-xz));
            const float ng = tanhf(fmaf(rg, xhn, xin));
            out_h[(size_t)idx * 128 + c] = fmaf(zg, hp - ng, ng);
        }
    }
}

extern "C" void kernel_launch(void* const* d_in, const int* in_sizes, int n_in,
                              void* d_out, int out_size, void* d_ws, size_t ws_size,
                              hipStream_t stream) {
    const float* h         = (const float*)d_in[0];
    const float* p         = (const float*)d_in[1];
    const float* X_obs     = (const float*)d_in[2];
    const float* M_obs     = (const float*)d_in[3];
    const int*   i_obs     = (const int*)d_in[4];
    const float* w_prep    = (const float*)d_in[5];
    const float* bias_prep = (const float*)d_in[6];
    const float* W_ih      = (const float*)d_in[7];
    const float* W_hh      = (const float*)d_in[8];
    const float* b_ih      = (const float*)d_in[9];
    const float* b_hh      = (const float*)d_in[10];

    const int Nh   = in_sizes[0] / 128;   // 500000
    const int NOBS = in_sizes[4];         // 200000

    float* out_h      = (float*)d_out;
    float* out_losses = out_h + (size_t)Nh * 128;
    unsigned short* Bpk = (unsigned short*)d_ws;   // 98304 bf16 = 192 KB

    hipLaunchKernelGGL(k_prepack, dim3(98304 / 256), dim3(256), 0, stream,
                       W_ih, W_hh, Bpk);

    long n4 = (long)Nh * 128 / 4;
    hipLaunchKernelGGL(k_copy, dim3(2048), dim3(256), 0, stream,
                       (const float4*)h, (float4*)out_h, n4);

    hipLaunchKernelGGL(k_main, dim3(NOBS / 64), dim3(512), 0, stream,
                       h, p, X_obs, M_obs, i_obs, w_prep, bias_prep, Bpk,
                       b_ih, b_hh, out_h, out_losses);
}